// Round 4
// baseline (1148.504 us; speedup 1.0000x reference)
//
#include <hip/hip_runtime.h>

typedef unsigned short u16;
typedef unsigned int u32;
using bfrag = __attribute__((ext_vector_type(8))) short;   // 8 x bf16 (raw bits)
using facc  = __attribute__((ext_vector_type(4))) float;   // MFMA accumulator

typedef __attribute__((address_space(3))) void lds_void;
typedef __attribute__((address_space(1))) const void glb_void;

// ---------------- numeric helpers ----------------
__device__ __forceinline__ u16 f2b(float f) {              // f32 -> bf16 (RNE)
  u32 u = __float_as_uint(f);
  return (u16)((u + 0x7FFFu + ((u >> 16) & 1u)) >> 16);
}
__device__ __forceinline__ float b2f(u16 h) { return __uint_as_float(((u32)h) << 16); }
__device__ __forceinline__ u32 encf(float f) {             // order-preserving f32->u32
  u32 u = __float_as_uint(f);
  return (u & 0x80000000u) ? ~u : (u | 0x80000000u);
}
__device__ __forceinline__ float decf(u32 e) {
  return __uint_as_float((e & 0x80000000u) ? (e & 0x7FFFFFFFu) : ~e);
}
__device__ __forceinline__ float mish_f(float v) {
  if (v > 15.f) return v;
  float ev = __expf(v);
  float p = ev * (ev + 2.f);
  return v * p / (p + 2.f);
}
__device__ __forceinline__ float ldf(const void* p, int i, int bf) {
  return bf ? b2f(((const u16*)p)[i]) : ((const float*)p)[i];
}
// Swizzled LDS tile [96][256] bf16: row stride 512B, XOR swizzle bits 4..6.
__device__ __forceinline__ u16* tptr(char* base, int row, int col) {
  int byt = ((row << 9) + (col << 1)) ^ ((row & 7) << 4);
  return (u16*)(base + byt);
}
// raw barrier: drain own LDS ops, sync; vmem (DMA prefetch) stays in flight
__device__ __forceinline__ void barrier_lds() {
  asm volatile("s_waitcnt lgkmcnt(0)" ::: "memory");
  __builtin_amdgcn_s_barrier();
  __builtin_amdgcn_sched_barrier(0);
}
// async global->LDS DMA, 16B per lane, linear LDS dest
__device__ __forceinline__ void dma16(const void* g, void* l) {
  __builtin_amdgcn_global_load_lds((glb_void*)g, (lds_void*)l, 16, 0, 0);
}
// prefetch one element's x (rows 0..80, 41472B) into swizzled bufX:
// linear LDS dest, inverse-swizzled global source (m173 pattern)
__device__ __forceinline__ void prefetch_x(const char* xb, char* bufX, int tid) {
  #pragma unroll
  for (int c = 0; c < 6; ++c) {
    int idx = tid + (c << 9);
    if (idx < 2592) {
      int row = idx >> 5;
      int wb = (idx & 31) << 4;
      const char* src = xb + (row << 9) + (wb ^ ((row & 7) << 4));
      dma16(src, bufX + (idx << 4));
    }
  }
}

// ---------------- dtype detector ----------------
__global__ void detect_dtype_kernel(const void* __restrict__ x, int* __restrict__ flag) {
  __shared__ int cnt;
  const int tid = threadIdx.x;
  if (tid == 0) cnt = 0;
  __syncthreads();
  const u16* p = (const u16*)x;
  u16 h = p[tid * 96 + 4];
  int e = (int)((h >> 7) & 0xFF);
  if (e >= 116 && e <= 134) atomicAdd(&cnt, 1);
  __syncthreads();
  if (tid == 0) *flag = (cnt >= 128) ? 1 : 0;
}

// ---------------- prep kernels ----------------
// W_embed[k][n] -> MFMA-tiled Wt_tl (B-fragment layout, n-major tiles). grid 256(k), 256thr(n).
__global__ void prep_wemb_tiled(const void* __restrict__ W, u16* __restrict__ Wt_tl,
                                const int* __restrict__ flag) {
  const int k = blockIdx.x, n = threadIdx.x;
  const int bf = *flag;
  u16 v = bf ? ((const u16*)W)[(k << 8) + n] : f2b(((const float*)W)[(k << 8) + n]);
  int nt = n >> 4, lr = n & 15, kt = k >> 5, lg = (k >> 3) & 3, e = k & 7;
  Wt_tl[(size_t)(((nt << 3) + kt) << 9) + (((lg << 4) + lr) << 3) + e] = v;
}

// Wqkt_tl[(n,k) tiled] = (Wq @ Wk^T)[k][n]. grid 256 (n), 256 thr (k).
__global__ void prep_wqk_tiled(const void* __restrict__ Wq, const void* __restrict__ Wk,
                               u16* __restrict__ Wqkt_tl, const int* __restrict__ flag) {
  __shared__ float wkrow[256];
  __shared__ u16 wqt[64][260];
  const int bf = *flag;
  const int n = blockIdx.x, k = threadIdx.x;
  wkrow[k] = ldf(Wk, (n << 8) + k, bf);
  float s = 0.f;
  for (int d0 = 0; d0 < 256; d0 += 64) {
    __syncthreads();
    for (int it = 0; it < 64; ++it) {
      int kk = (it << 2) + (threadIdx.x >> 6);
      int dd = threadIdx.x & 63;
      wqt[dd][kk] = f2b(ldf(Wq, (kk << 8) + d0 + dd, bf));
    }
    __syncthreads();
    #pragma unroll 8
    for (int dd = 0; dd < 64; ++dd) s += b2f(wqt[dd][k]) * wkrow[d0 + dd];
  }
  int nt = n >> 4, lr = n & 15, kt = k >> 5, lg = (k >> 3) & 3, e = k & 7;
  Wqkt_tl[(size_t)(((nt << 3) + kt) << 9) + (((lg << 4) + lr) << 3) + e] = f2b(s);
}

// dqkp[q][d]=sum_n Wk[d][n]*dq[q][n]; uvec=Wq@bk; wvec=Wk@bq; dqc[q]=dq_q.bk, dqc[7]=bq.bk
__global__ void prep_vec_kernel(const void* __restrict__ Wq, const void* __restrict__ Wk,
                                const void* __restrict__ bq, const void* __restrict__ bk,
                                const void* __restrict__ dq,
                                u16* __restrict__ dqkp, float* __restrict__ uvec,
                                float* __restrict__ wvec, float* __restrict__ dqc,
                                const int* __restrict__ flag) {
  const int bf = *flag;
  const int blk = blockIdx.x, d = threadIdx.x;
  if (blk < 16) {
    float s = 0.f;
    if (blk < 7)
      for (int nn = 0; nn < 256; ++nn)
        s += ldf(Wk, (d << 8) + nn, bf) * ldf(dq, (blk << 8) + nn, bf);
    dqkp[(blk << 8) + d] = f2b(s);
  } else if (blk == 16) {
    float su = 0.f, sw = 0.f;
    for (int nn = 0; nn < 256; ++nn) {
      su += ldf(Wq, (d << 8) + nn, bf) * ldf(bk, nn, bf);
      sw += ldf(Wk, (d << 8) + nn, bf) * ldf(bq, nn, bf);
    }
    uvec[d] = su; wvec[d] = sw;
  } else {
    if (d < 7) {
      float s = 0.f;
      for (int nn = 0; nn < 256; ++nn) s += ldf(dq, (d << 8) + nn, bf) * ldf(bk, nn, bf);
      dqc[d] = s;
    } else if (d == 7) {
      float s = 0.f;
      for (int nn = 0; nn < 256; ++nn) s += ldf(bq, nn, bf) * ldf(bk, nn, bf);
      dqc[7] = s;
    }
  }
}

// packed inverse table: invP[m] = (slot1+1) | ((slot2+1)<<16), 0 = none
__global__ void prep_invP_init(u32* __restrict__ invP) {
  int i = blockIdx.x * 256 + threadIdx.x;
  if (i < 6561) invP[i] = 0u;
}
__global__ void prep_invP_scatter(const int* __restrict__ vi, const int* __restrict__ pi,
                                  const int* __restrict__ qi, const int* __restrict__ qpi,
                                  int nv, int np, u32* __restrict__ invP) {
  int i = blockIdx.x * 256 + threadIdx.x;
  if (i < nv) atomicOr(&invP[vi[i]], (u32)(pi[i] + 1));
  if (i < np) atomicOr(&invP[qi[i]], ((u32)(qpi[i] + 1)) << 16);
}

// ---------------- persistent fused kernel ----------------
// LDS: bufX [96][256] swz (x, DMA dest)   @      0 (49152)
//      bufP [96][256] swz (pe)            @  49152 (49152)
//      bufT [96][256] swz ([T;dqkp;u;w;0])@  98304 (49152)
//      pol  [2187] u32 (+pad)             @ 147456 ( 8768)
//      alpha[96] f32                      @ 156224 (  384)
//      beta [96] f32                      @ 156608 (  384)
//      dqcS [8] f32 (+pad)                @ 156992 (   64)
#define LDS_TOTAL 157056

__global__ __launch_bounds__(512, 2)
void dirpolicy_pers(const void* __restrict__ x,
                    const void* __restrict__ b_embed,
                    const u16* __restrict__ Wt_tl,
                    const u16* __restrict__ Wqkt_tl,
                    const u16* __restrict__ dqkp,
                    const float* __restrict__ uvec,
                    const float* __restrict__ wvec,
                    const float* __restrict__ dqc,
                    const u32* __restrict__ invP,
                    void* __restrict__ out,
                    const int* __restrict__ dflag,
                    int Btot) {
  extern __shared__ char smem[];
  char* bufX = smem;
  char* bufP = smem + 49152;
  char* bufT = smem + 98304;
  u32* pol = (u32*)(smem + 147456);
  float* alpha = (float*)(smem + 156224);
  float* beta  = (float*)(smem + 156608);
  float* dqcS  = (float*)(smem + 156992);

  const int tid = threadIdx.x;
  const int lane = tid & 63;
  const int w = tid >> 6;
  const int lr = lane & 15;
  const int lg = lane >> 4;
  const int isbf = *dflag;
  const u32 ENEG = encf(-1e10f);
  const int wr = w >> 2, wc = w & 3;            // phase1/3: 2x4 wave grid
  const int wr4 = (w >= 3) ? 1 : 0;             // phase4: 2x3 wave grid (w<6)
  const int wc4 = w - wr4 * 3;

  // ---- prologue ----
  // issue first x DMA as early as possible
  if (isbf && (int)blockIdx.x < Btot)
    prefetch_x((const char*)x + (size_t)blockIdx.x * 41472u, bufX, tid);
  __builtin_amdgcn_sched_barrier(0);

  // per-thread packed inverse-table registers (constant across elements)
  u32 ivr[3][2][4];
  #pragma unroll
  for (int i = 0; i < 3; ++i)
    #pragma unroll
    for (int j = 0; j < 2; ++j)
      #pragma unroll
      for (int r = 0; r < 4; ++r) {
        int rowb = wr4 * 48 + i * 16 + (lg << 2) + r;
        int colb = wc4 * 32 + j * 16 + lr;
        ivr[i][j][r] = (w < 6 && rowb < 81 && colb < 81) ? invP[rowb * 81 + colb] : 0u;
      }
  // loop-invariant bias values for this thread's 4 output cols
  float biasv[4];
  #pragma unroll
  for (int j = 0; j < 4; ++j) biasv[j] = ldf(b_embed, (wc << 6) + j * 16 + lr, isbf);

  // constant LDS: bufT rows 81..87 = dqkp, 88 = uvec, 89 = wvec, 90..95 = 0; pol; dqcS
  for (int i = tid; i < 1792; i += 512) {
    int q = i >> 8, k = i & 255;
    *tptr(bufT, 81 + q, k) = dqkp[(q << 8) + k];
  }
  {
    int rowk = tid;                               // rows 88,89 (512 entries)
    int rrr = 88 + (rowk >> 8), k = rowk & 255;
    *tptr(bufT, rrr, k) = f2b((rrr == 88) ? uvec[k] : wvec[k]);
  }
  for (int i = tid; i < 1536; i += 512)
    *tptr(bufT, 90 + (i >> 8), i & 255) = 0;
  for (int i = tid; i < 2187; i += 512) pol[i] = ENEG;
  if (tid < 8) dqcS[tid] = dqc[tid];

  // ---- persistent element loop ----
  for (int b = blockIdx.x; b < Btot; b += (int)gridDim.x) {
    // TOP barrier: land DMA'd x (+ drain everything) and make consts/pol visible
    asm volatile("s_waitcnt vmcnt(0) lgkmcnt(0)" ::: "memory");
    __builtin_amdgcn_s_barrier();
    __builtin_amdgcn_sched_barrier(0);

    if (!isbf) {   // synchronous f32 staging path
      const float4* xs = (const float4*)((const float*)x + (size_t)b * 20736u);
      #pragma unroll
      for (int c = 0; c < 11; ++c) {
        int i = tid + (c << 9);
        if (i < 5184) {
          float4 v = xs[i];
          ushort4 h;
          h.x = f2b(v.x); h.y = f2b(v.y); h.z = f2b(v.z); h.w = f2b(v.w);
          *(ushort4*)tptr(bufX, i >> 6, (i & 63) << 2) = h;
        }
      }
      asm volatile("s_waitcnt lgkmcnt(0)" ::: "memory");
      __builtin_amdgcn_s_barrier();
    }

    // ===== phase 1: pe = mish(x @ We + b) -> bufP =====
    {
      facc acc[3][4];
      facc z4 = {0.f, 0.f, 0.f, 0.f};
      #pragma unroll
      for (int i = 0; i < 3; ++i)
        #pragma unroll
        for (int j = 0; j < 4; ++j) acc[i][j] = z4;
      #pragma unroll
      for (int kt = 0; kt < 8; ++kt) {
        bfrag bb[4], a[3];
        #pragma unroll
        for (int j = 0; j < 4; ++j)
          bb[j] = *(const bfrag*)(Wt_tl + (size_t)(((((wc << 2) + j) << 3) + kt) << 9) + (lane << 3));
        #pragma unroll
        for (int i = 0; i < 3; ++i)
          a[i] = *(const bfrag*)tptr(bufX, wr * 48 + i * 16 + lr, (kt << 5) + (lg << 3));
        #pragma unroll
        for (int i = 0; i < 3; ++i)
          #pragma unroll
          for (int j = 0; j < 4; ++j)
            acc[i][j] = __builtin_amdgcn_mfma_f32_16x16x32_bf16(a[i], bb[j], acc[i][j], 0, 0, 0);
      }
      #pragma unroll
      for (int j = 0; j < 4; ++j) {
        const int col = (wc << 6) + j * 16 + lr;
        #pragma unroll
        for (int i = 0; i < 3; ++i)
          #pragma unroll
          for (int r = 0; r < 4; ++r) {
            const int row = wr * 48 + i * 16 + (lg << 2) + r;
            *tptr(bufP, row, col) = f2b(mish_f(acc[i][j][r] + biasv[j]));
          }
      }
    }
    barrier_lds();   // A: x reads done, pe visible (no vmem drain)

    // t1: issue ALL phase-3 B fragments, then the next element's x DMA
    bfrag B2r[8][4];
    #pragma unroll
    for (int kt = 0; kt < 8; ++kt)
      #pragma unroll
      for (int j = 0; j < 4; ++j)
        B2r[kt][j] = *(const bfrag*)(Wqkt_tl + (size_t)(((((wc << 2) + j) << 3) + kt) << 9) + (lane << 3));
    __builtin_amdgcn_sched_barrier(0);
    if (isbf) {
      int bn = b + (int)gridDim.x;
      if (bn < Btot) prefetch_x((const char*)x + (size_t)bn * 41472u, bufX, tid);
    }
    __builtin_amdgcn_sched_barrier(0);

    // ===== phase 3: T = pe @ Wqk -> bufT rows 0..80 =====
    {
      facc acc2[3][4];
      facc z4 = {0.f, 0.f, 0.f, 0.f};
      #pragma unroll
      for (int i = 0; i < 3; ++i)
        #pragma unroll
        for (int j = 0; j < 4; ++j) acc2[i][j] = z4;
      #pragma unroll
      for (int kt = 0; kt < 8; ++kt) {
        bfrag a[3];
        #pragma unroll
        for (int i = 0; i < 3; ++i)
          a[i] = *(const bfrag*)tptr(bufP, wr * 48 + i * 16 + lr, (kt << 5) + (lg << 3));
        #pragma unroll
        for (int i = 0; i < 3; ++i)
          #pragma unroll
          for (int j = 0; j < 4; ++j)
            acc2[i][j] = __builtin_amdgcn_mfma_f32_16x16x32_bf16(a[i], B2r[kt][j], acc2[i][j], 0, 0, 0);
      }
      #pragma unroll
      for (int i = 0; i < 3; ++i)
        #pragma unroll
        for (int j = 0; j < 4; ++j) {
          const int col = (wc << 6) + j * 16 + lr;
          #pragma unroll
          for (int r = 0; r < 4; ++r) {
            const int row = wr * 48 + i * 16 + (lg << 2) + r;
            if (row < 81) *tptr(bufT, row, col) = f2b(acc2[i][j][r]);
          }
        }
    }
    barrier_lds();   // B: T visible (prefetch still in flight)

    // ===== phase 4: board = [T;dqkp;u;w] @ pe^T =====
    facc bd[3][2];
    {
      facc z4 = {0.f, 0.f, 0.f, 0.f};
      #pragma unroll
      for (int i = 0; i < 3; ++i)
        #pragma unroll
        for (int j = 0; j < 2; ++j) bd[i][j] = z4;
    }
    if (w < 6) {
      #pragma unroll
      for (int kt = 0; kt < 8; ++kt) {
        bfrag a[3], bb[2];
        #pragma unroll
        for (int i = 0; i < 3; ++i)
          a[i] = *(const bfrag*)tptr(bufT, wr4 * 48 + i * 16 + lr, (kt << 5) + (lg << 3));
        #pragma unroll
        for (int j = 0; j < 2; ++j)
          bb[j] = *(const bfrag*)tptr(bufP, wc4 * 32 + j * 16 + lr, (kt << 5) + (lg << 3));
        #pragma unroll
        for (int i = 0; i < 3; ++i)
          #pragma unroll
          for (int j = 0; j < 2; ++j)
            bd[i][j] = __builtin_amdgcn_mfma_f32_16x16x32_bf16(a[i], bb[j], bd[i][j], 0, 0, 0);
      }
      // rows 88/89 hold pe.u / pe.w -> alpha/beta (writers: wr4==1, lg==2, r=0/1)
      if (wr4 == 1 && lg == 2) {
        const float c7 = dqcS[7];
        #pragma unroll
        for (int j = 0; j < 2; ++j) {
          const int colb = wc4 * 32 + j * 16 + lr;
          alpha[colb] = (bd[2][j][0] + c7) * 0.0625f;
          beta[colb]  = bd[2][j][1] * 0.0625f;
        }
      }
    }
    barrier_lds();   // B2: alpha/beta visible (uniform)

    // scatter straight from accumulators
    if (w < 6) {
      float betv[2];
      #pragma unroll
      for (int j = 0; j < 2; ++j) {
        int colb = wc4 * 32 + j * 16 + lr;
        betv[j] = (colb < 81) ? beta[colb] : 0.f;
      }
      #pragma unroll
      for (int i = 0; i < 3; ++i)
        #pragma unroll
        for (int r = 0; r < 4; ++r) {
          const int rowb = wr4 * 48 + i * 16 + (lg << 2) + r;
          if (rowb < 81) {
            const float av = alpha[rowb];
            #pragma unroll
            for (int j = 0; j < 2; ++j) {
              const int colb = wc4 * 32 + j * 16 + lr;
              if (colb < 81) {
                const u32 ev = encf(bd[i][j][r] * 0.0625f + av + betv[j]);
                const u32 pv = ivr[i][j][r];
                if (pv & 0xFFFFu) atomicMax(&pol[(pv & 0xFFFFu) - 1], ev);
                if (pv >> 16)     atomicMax(&pol[(pv >> 16) - 1], ev);
              }
            }
          } else if (rowb < 88) {
            const float dv = dqcS[rowb - 81];
            #pragma unroll
            for (int j = 0; j < 2; ++j) {
              const int colb = wc4 * 32 + j * 16 + lr;
              if (colb < 81)
                pol[1620 + (rowb - 81) * 81 + colb] = encf((bd[i][j][r] + dv) * 0.0625f);
            }
          }
        }
    }
    barrier_lds();   // C: pol complete

    // decode + store + re-init pol for next element
    if (isbf) {
      u16* ob = (u16*)out + (size_t)b * 2187u;
      for (int p2 = tid; p2 < 2187; p2 += 512) {
        u32 v = pol[p2]; pol[p2] = ENEG;
        ob[p2] = f2b(decf(v));
      }
    } else {
      float* ob = (float*)out + (size_t)b * 2187u;
      for (int p2 = tid; p2 < 2187; p2 += 512) {
        u32 v = pol[p2]; pol[p2] = ENEG;
        ob[p2] = decf(v);
      }
    }
  }
}

// ---------------- launcher ----------------
extern "C" void kernel_launch(void* const* d_in, const int* in_sizes, int n_in,
                              void* d_out, int out_size, void* d_ws, size_t ws_size,
                              hipStream_t stream) {
  const void* x        = d_in[0];
  const void* W_embed  = d_in[1];
  const void* b_embed  = d_in[2];
  const void* Wq       = d_in[3];
  const void* bq       = d_in[4];
  const void* Wk       = d_in[5];
  const void* bk_      = d_in[6];
  const void* dq       = d_in[7];
  const int* valid_idx         = (const int*)d_in[8];
  const int* policy_idx        = (const int*)d_in[9];
  const int* promo_idx         = (const int*)d_in[10];
  const int* promo_policy_idx  = (const int*)d_in[11];
  const int n_valid = in_sizes[8];
  const int n_promo = in_sizes[10];
  const int B = in_sizes[0] / 20736;   // 81*256

  // ws layout
  char* ws = (char*)d_ws;
  u16* Wt_tl    = (u16*)(ws);               // 131072
  u16* Wqkt_tl  = (u16*)(ws + 131072);      // 131072
  u16* dqkp     = (u16*)(ws + 262144);      // 8192
  float* uvec   = (float*)(ws + 270336);    // 1024
  float* wvec   = (float*)(ws + 271360);    // 1024
  float* dqc    = (float*)(ws + 272384);    // 64
  int* dflag    = (int*)(ws + 272448);      // 64
  u32* invP     = (u32*)(ws + 272512);      // 26244 (+pad)
  if (ws_size < 298816) return;

  detect_dtype_kernel<<<dim3(1), dim3(256), 0, stream>>>(x, dflag);
  prep_wemb_tiled<<<dim3(256), dim3(256), 0, stream>>>(W_embed, Wt_tl, dflag);
  prep_wqk_tiled<<<dim3(256), dim3(256), 0, stream>>>(Wq, Wk, Wqkt_tl, dflag);
  prep_vec_kernel<<<dim3(18), dim3(256), 0, stream>>>(Wq, Wk, bq, bk_, dq,
                                                      dqkp, uvec, wvec, dqc, dflag);
  prep_invP_init<<<dim3(26), dim3(256), 0, stream>>>(invP);
  int mx = n_valid > n_promo ? n_valid : n_promo;
  prep_invP_scatter<<<dim3((mx + 255) / 256), dim3(256), 0, stream>>>(
      valid_idx, policy_idx, promo_idx, promo_policy_idx, n_valid, n_promo, invP);

  (void)hipFuncSetAttribute((const void*)dirpolicy_pers,
                            hipFuncAttributeMaxDynamicSharedMemorySize, LDS_TOTAL);
  int grid = B < 256 ? B : 256;
  dirpolicy_pers<<<dim3(grid), dim3(512), LDS_TOTAL, stream>>>(
      x, b_embed, Wt_tl, Wqkt_tl, dqkp, uvec, wvec, dqc, invP, d_out, dflag, B);
}